// Round 1
// baseline (377.365 us; speedup 1.0000x reference)
//
#include <hip/hip_runtime.h>

// B-spline basis (Cox-de Boor), degree 3, 12 knots -> 8 basis functions.
// x: (1024, 8192) f32, knots: (12,) f32, out: (1024, 8192, 8) f32.
// Memory-bound: 32 MiB read + 256 MiB write. Strategy: fully-unrolled
// register-resident recurrence, reciprocal denominators hoisted out of the
// grid-stride loop, float4 loads of x (4 elements/thread) and float4 stores
// (128 contiguous bytes per thread per iteration).

__global__ __launch_bounds__(256) void bspline_kernel(
    const float* __restrict__ x, const float* __restrict__ knots,
    float* __restrict__ out, int n4) {
  // Knots are uniform across the grid: 12 scalar loads (compiler emits s_load).
  float k[12];
#pragma unroll
  for (int i = 0; i < 12; ++i) k[i] = knots[i];

  // Reciprocal denominators for the three Cox-de Boor levels.
  // left_den[d][i]  = k[i+d]-k[i]  -> invd[d][i]
  // right_den[d][i] = k[i+d+1]-k[i+1] = left_den[d][i+1]
  float i1[11], i2[10], i3[9];
#pragma unroll
  for (int i = 0; i < 11; ++i) i1[i] = 1.0f / (k[i + 1] - k[i]);
#pragma unroll
  for (int i = 0; i < 10; ++i) i2[i] = 1.0f / (k[i + 2] - k[i]);
#pragma unroll
  for (int i = 0; i < 9; ++i) i3[i] = 1.0f / (k[i + 3] - k[i]);

  const float4* __restrict__ x4 = reinterpret_cast<const float4*>(x);
  const int stride = gridDim.x * blockDim.x;

  for (int v = blockIdx.x * blockDim.x + threadIdx.x; v < n4; v += stride) {
    const float4 xv = x4[v];
    const float t4[4] = {xv.x, xv.y, xv.z, xv.w};
    float4* o = reinterpret_cast<float4*>(out) + (size_t)v * 8;

#pragma unroll
    for (int e = 0; e < 4; ++e) {
      const float t = t4[e];

      // t - k[i]; the right-hand numerator k[j] - t is just the negation,
      // folded into the FMA as -tm[j]*inv.
      float tm[12];
#pragma unroll
      for (int i = 0; i < 12; ++i) tm[i] = t - k[i];

      // Level 0: half-open interval indicators [k[i], k[i+1]).
      float B[11];
#pragma unroll
      for (int i = 0; i < 11; ++i)
        B[i] = (k[i] <= t && t < k[i + 1]) ? 1.0f : 0.0f;

      // Level 1 (10 funcs), level 2 (9), level 3 (8).
#pragma unroll
      for (int i = 0; i < 10; ++i)
        B[i] = tm[i] * i1[i] * B[i] - tm[i + 2] * i1[i + 1] * B[i + 1];
#pragma unroll
      for (int i = 0; i < 9; ++i)
        B[i] = tm[i] * i2[i] * B[i] - tm[i + 3] * i2[i + 1] * B[i + 1];
#pragma unroll
      for (int i = 0; i < 8; ++i)
        B[i] = tm[i] * i3[i] * B[i] - tm[i + 4] * i3[i + 1] * B[i + 1];

      // 32 contiguous bytes per element; 128 contiguous bytes per thread/iter.
      o[e * 2 + 0] = make_float4(B[0], B[1], B[2], B[3]);
      o[e * 2 + 1] = make_float4(B[4], B[5], B[6], B[7]);
    }
  }
}

extern "C" void kernel_launch(void* const* d_in, const int* in_sizes, int n_in,
                              void* d_out, int out_size, void* d_ws, size_t ws_size,
                              hipStream_t stream) {
  const float* x = (const float*)d_in[0];
  const float* knots = (const float*)d_in[1];
  float* out = (float*)d_out;
  const int n = in_sizes[0];   // 1024*8192 = 8388608, divisible by 4
  const int n4 = n >> 2;
  // Memory-bound: ~2048 blocks (8/CU) + grid-stride.
  const int blocks = 2048;
  bspline_kernel<<<blocks, 256, 0, stream>>>(x, knots, out, n4);
}

// Round 2
// 295.140 us; speedup vs baseline: 1.2786x; 1.2786x over previous
//
#include <hip/hip_runtime.h>

// B-spline basis (Cox-de Boor), degree 3, 12 knots -> 8 basis functions.
// x: (1024, 8192) f32, knots: (12,) f32, out: (1024, 8192, 8) f32.
//
// R1 lesson: per-thread-contiguous 128-B output chunks made every wave store
// instruction a 128-B-lane-stride scatter (64 L2 requests/instr) -> 0.8 TB/s.
// R2: stage the 8-float-per-element output through a column-major LDS tile,
// then store cooperatively with 16-B lane stride (perfect coalescing).
//
// LDS layout: lds[j*TILE + le] = B_j(element le).
//   write: lane stride 4 B  -> conflict-free (2-way alias is free, m136)
//   read:  lanes 2m/2m+1 share le, j differs by 4 -> same bank, 2-way, free
//   store: float4 f4 = s*256+c covers element f4>>1, basis 4*(f4&1)..+3;
//          lane stride 16 B -> fully coalesced 4 KiB per instruction.

#define TILE 512  // elements per block-iteration; LDS = 8*512*4 = 16 KiB

__global__ __launch_bounds__(256) void bspline_kernel(
    const float* __restrict__ x, const float* __restrict__ knots,
    float* __restrict__ out, int ntiles) {
  __shared__ float lds[8 * TILE];

  // Knots are wave-uniform: scalar loads.
  float k[12];
#pragma unroll
  for (int i = 0; i < 12; ++i) k[i] = knots[i];

  // Reciprocal denominators, hoisted (right_den[d][i] == left_den[d][i+1]).
  float i1[11], i2[10], i3[9];
#pragma unroll
  for (int i = 0; i < 11; ++i) i1[i] = 1.0f / (k[i + 1] - k[i]);
#pragma unroll
  for (int i = 0; i < 10; ++i) i2[i] = 1.0f / (k[i + 2] - k[i]);
#pragma unroll
  for (int i = 0; i < 9; ++i) i3[i] = 1.0f / (k[i + 3] - k[i]);

  for (int tile = blockIdx.x; tile < ntiles; tile += gridDim.x) {
    const int base = tile * TILE;

    // ---- compute phase: 2 elements/thread, coalesced 4-B x loads ----
#pragma unroll
    for (int q = 0; q < 2; ++q) {
      const int le = q * 256 + threadIdx.x;
      const float t = x[base + le];

      float tm[12];
#pragma unroll
      for (int i = 0; i < 12; ++i) tm[i] = t - k[i];

      float B[11];
#pragma unroll
      for (int i = 0; i < 11; ++i)
        B[i] = (k[i] <= t && t < k[i + 1]) ? 1.0f : 0.0f;

#pragma unroll
      for (int i = 0; i < 10; ++i)
        B[i] = tm[i] * i1[i] * B[i] - tm[i + 2] * i1[i + 1] * B[i + 1];
#pragma unroll
      for (int i = 0; i < 9; ++i)
        B[i] = tm[i] * i2[i] * B[i] - tm[i + 3] * i2[i + 1] * B[i + 1];
#pragma unroll
      for (int i = 0; i < 8; ++i)
        B[i] = tm[i] * i3[i] * B[i] - tm[i + 4] * i3[i + 1] * B[i + 1];

      // Column-major LDS write: lane stride 4 B, conflict-free.
#pragma unroll
      for (int j = 0; j < 8; ++j) lds[j * TILE + le] = B[j];
    }
    __syncthreads();

    // ---- store phase: 4 float4/thread, perfectly coalesced ----
    float4* o4 = reinterpret_cast<float4*>(out) + (size_t)base * 2;
#pragma unroll
    for (int s = 0; s < 4; ++s) {
      const int f4 = s * 256 + threadIdx.x;
      const int le = f4 >> 1;          // element index within tile
      const int j0 = (f4 & 1) * 4;     // basis offset (0 or 4)
      float4 v;
      v.x = lds[(j0 + 0) * TILE + le];
      v.y = lds[(j0 + 1) * TILE + le];
      v.z = lds[(j0 + 2) * TILE + le];
      v.w = lds[(j0 + 3) * TILE + le];
      o4[f4] = v;
    }
    __syncthreads();  // protect LDS before next tile overwrites it
  }
}

extern "C" void kernel_launch(void* const* d_in, const int* in_sizes, int n_in,
                              void* d_out, int out_size, void* d_ws, size_t ws_size,
                              hipStream_t stream) {
  const float* x = (const float*)d_in[0];
  const float* knots = (const float*)d_in[1];
  float* out = (float*)d_out;
  const int n = in_sizes[0];       // 8388608, divisible by TILE
  const int ntiles = n / TILE;     // 16384
  const int blocks = 2048;         // 8 blocks/CU resident (16 KiB LDS each)
  bspline_kernel<<<blocks, 256, 0, stream>>>(x, knots, out, ntiles);
}

// Round 7
// 293.801 us; speedup vs baseline: 1.2844x; 1.0046x over previous
//
#include <hip/hip_runtime.h>

// B-spline basis (Cox-de Boor), degree 3, 12 knots -> 8 basis functions.
// x: (1024, 8192) f32, knots: (12,) f32, out: (1024, 8192, 8) f32.
//
// R1: per-thread 128-B output chunks -> 128-B lane-stride store scatter
//     (64 L2 requests/instr) -> kernel ~150 us.
// R2: LDS transpose -> coalesced stores -> kernel ~67 us (dur_us also carries
//     a ~228-us harness reset floor: 1 GiB ws poison + out poison + x restore;
//     evidence: kernel never appears in rocprof top-5, fills at ~170 us do).
// R3: ping-pong LDS (one barrier/tile instead of two), x prefetch issued
//     before the store phase (HBM latency hides under stores), float2 x
//     loads, ds_write_b64 LDS writes, nontemporal loads/stores (pure stream,
//     zero reuse -> keep it out of L2). Target kernel ~52 us.
//     (Resubmitted unchanged 4x: R3/R4/R6 acquisition timeouts, R5 container
//     failure — kernel never reached hardware.)

#define TILE 512  // elements per tile; LDS = 2 bufs * 8*512*4 B = 32 KiB

typedef float vf4 __attribute__((ext_vector_type(4)));
typedef float vf2 __attribute__((ext_vector_type(2)));

__device__ __forceinline__ void compute_pair(
    vf2 xv, const float* __restrict__ k,
    const float* __restrict__ i1, const float* __restrict__ i2,
    const float* __restrict__ i3, float* __restrict__ buf, int tid) {
  float Ba[2][8];
#pragma unroll
  for (int e = 0; e < 2; ++e) {
    const float t = xv[e];

    float tm[12];
#pragma unroll
    for (int i = 0; i < 12; ++i) tm[i] = t - k[i];

    // Level 0: half-open interval indicators [k[i], k[i+1]).
    float B[11];
#pragma unroll
    for (int i = 0; i < 11; ++i)
      B[i] = (k[i] <= t && t < k[i + 1]) ? 1.0f : 0.0f;

#pragma unroll
    for (int i = 0; i < 10; ++i)
      B[i] = tm[i] * i1[i] * B[i] - tm[i + 2] * i1[i + 1] * B[i + 1];
#pragma unroll
    for (int i = 0; i < 9; ++i)
      B[i] = tm[i] * i2[i] * B[i] - tm[i + 3] * i2[i + 1] * B[i + 1];
#pragma unroll
    for (int i = 0; i < 8; ++i)
      B[i] = tm[i] * i3[i] * B[i] - tm[i + 4] * i3[i + 1] * B[i + 1];

#pragma unroll
    for (int j = 0; j < 8; ++j) Ba[e][j] = B[j];
  }
  // Column-major: buf[j*TILE + 2*tid + e]; both elements as one b64 write.
  // Lane stride 8 B -> contiguous 512 B per wave instr, conflict-free.
  vf2* b2 = reinterpret_cast<vf2*>(buf);
#pragma unroll
  for (int j = 0; j < 8; ++j) {
    vf2 v;
    v[0] = Ba[0][j];
    v[1] = Ba[1][j];
    b2[j * (TILE / 2) + tid] = v;
  }
}

__global__ __launch_bounds__(256) void bspline_kernel(
    const float* __restrict__ x, const float* __restrict__ knots,
    float* __restrict__ out, int ntiles) {
  __shared__ float lds[2][8 * TILE];

  // Knots are wave-uniform scalar loads; reciprocal denominators hoisted.
  float k[12];
#pragma unroll
  for (int i = 0; i < 12; ++i) k[i] = knots[i];
  float i1[11], i2[10], i3[9];
#pragma unroll
  for (int i = 0; i < 11; ++i) i1[i] = 1.0f / (k[i + 1] - k[i]);
#pragma unroll
  for (int i = 0; i < 10; ++i) i2[i] = 1.0f / (k[i + 2] - k[i]);
#pragma unroll
  for (int i = 0; i < 9; ++i) i3[i] = 1.0f / (k[i + 3] - k[i]);

  const int tid = threadIdx.x;
  const vf2* __restrict__ x2 = reinterpret_cast<const vf2*>(x);

  int t = blockIdx.x;
  if (t >= ntiles) return;

  // Prolog: compute tile t into buffer 0.
  vf2 xv = __builtin_nontemporal_load(&x2[t * (TILE / 2) + tid]);
  compute_pair(xv, k, i1, i2, i3, lds[0], tid);
  __syncthreads();

  int cur = 0;
  for (;;) {
    const int tn = t + gridDim.x;
    const bool more = tn < ntiles;

    // Issue next tile's x load BEFORE the store phase: HBM latency hides
    // under the 4 KiB of stores below.
    vf2 xn;
    if (more) xn = __builtin_nontemporal_load(&x2[tn * (TILE / 2) + tid]);

    // Store phase for tile t from lds[cur]: 4 float4/thread, 16-B lane
    // stride, perfectly coalesced. LDS reads are 2-way bank aliased (free).
    {
      const float* __restrict__ buf = lds[cur];
      vf4* o4 = reinterpret_cast<vf4*>(out) + (size_t)t * (TILE * 2);
#pragma unroll
      for (int s = 0; s < 4; ++s) {
        const int f4 = s * 256 + tid;
        const int le = f4 >> 1;
        const int j0 = (f4 & 1) * 4;
        vf4 v;
        v[0] = buf[(j0 + 0) * TILE + le];
        v[1] = buf[(j0 + 1) * TILE + le];
        v[2] = buf[(j0 + 2) * TILE + le];
        v[3] = buf[(j0 + 3) * TILE + le];
        __builtin_nontemporal_store(v, &o4[f4]);
      }
    }

    if (!more) break;

    // Compute next tile into the other buffer (no barrier needed between
    // reads of lds[cur] above and writes of lds[cur^1] here).
    compute_pair(xn, k, i1, i2, i3, lds[cur ^ 1], tid);
    __syncthreads();  // one barrier per tile: protects both buffers
    cur ^= 1;
    t = tn;
  }
}

extern "C" void kernel_launch(void* const* d_in, const int* in_sizes, int n_in,
                              void* d_out, int out_size, void* d_ws, size_t ws_size,
                              hipStream_t stream) {
  const float* x = (const float*)d_in[0];
  const float* knots = (const float*)d_in[1];
  float* out = (float*)d_out;
  const int n = in_sizes[0];       // 8388608, divisible by TILE
  const int ntiles = n / TILE;     // 16384
  const int blocks = 2048;         // 32 KiB LDS -> 5 blocks/CU, 20 waves/CU
  bspline_kernel<<<blocks, 256, 0, stream>>>(x, knots, out, ntiles);
}

// Round 8
// 289.437 us; speedup vs baseline: 1.3038x; 1.0151x over previous
//
#include <hip/hip_runtime.h>

// B-spline basis (Cox-de Boor), degree 3, 12 knots -> 8 basis functions.
// x: (1024, 8192) f32, knots: (12,) f32, out: (1024, 8192, 8) f32.
//
// R1: per-thread 128-B chunks -> store scatter -> kernel ~150 us.
// R2: block-wide LDS transpose + coalesced stores -> ~67 us (dur_us carries a
//     ~228-us harness re-poison floor; kernel never in rocprof top-5).
// R3/R7: ping-pong + prefetch + NT -> NULL (66 us). Barrier (+vmcnt drain)
//     kept all 4 waves phase-locked: stores issue in short bursts, VMEM pipe
//     idles between them (5 phase-groups/CU) -> 4.6 TB/s not 6.3.
// R8: barrier-FREE wave-private transpose. Each wave owns a 4-KiB LDS region
//     and transposes its own 128 elements; same-wave LDS ordering needs no
//     __syncthreads and no vmcnt drain. 16 KiB/block -> 8 blocks/CU
//     (32 waves/CU). Waves desynchronize -> smooth store issue. Depth-2 x
//     prefetch; NT stores only. Target kernel ~48-55 us.

#define SEG 128  // elements per wave-iteration; 8*128*4 B = 4 KiB per wave

typedef float vf4 __attribute__((ext_vector_type(4)));
typedef float vf2 __attribute__((ext_vector_type(2)));

__device__ __forceinline__ void compute_pair(
    vf2 xv, const float* __restrict__ k,
    const float* __restrict__ i1, const float* __restrict__ i2,
    const float* __restrict__ i3, float Ba[2][8]) {
#pragma unroll
  for (int e = 0; e < 2; ++e) {
    const float t = xv[e];

    float tm[12];
#pragma unroll
    for (int i = 0; i < 12; ++i) tm[i] = t - k[i];

    // Level 0: half-open interval indicators [k[i], k[i+1]).
    float B[11];
#pragma unroll
    for (int i = 0; i < 11; ++i)
      B[i] = (k[i] <= t && t < k[i + 1]) ? 1.0f : 0.0f;

#pragma unroll
    for (int i = 0; i < 10; ++i)
      B[i] = tm[i] * i1[i] * B[i] - tm[i + 2] * i1[i + 1] * B[i + 1];
#pragma unroll
    for (int i = 0; i < 9; ++i)
      B[i] = tm[i] * i2[i] * B[i] - tm[i + 3] * i2[i + 1] * B[i + 1];
#pragma unroll
    for (int i = 0; i < 8; ++i)
      B[i] = tm[i] * i3[i] * B[i] - tm[i + 4] * i3[i + 1] * B[i + 1];

#pragma unroll
    for (int j = 0; j < 8; ++j) Ba[e][j] = B[j];
  }
}

__global__ __launch_bounds__(256) void bspline_kernel(
    const float* __restrict__ x, const float* __restrict__ knots,
    float* __restrict__ out, int nseg) {
  // Wave-private LDS: no inter-wave sharing -> no barriers anywhere.
  __shared__ float lds[4][8 * SEG];

  // Knots are wave-uniform scalar loads; reciprocal denominators hoisted.
  float k[12];
#pragma unroll
  for (int i = 0; i < 12; ++i) k[i] = knots[i];
  float i1[11], i2[10], i3[9];
#pragma unroll
  for (int i = 0; i < 11; ++i) i1[i] = 1.0f / (k[i + 1] - k[i]);
#pragma unroll
  for (int i = 0; i < 10; ++i) i2[i] = 1.0f / (k[i + 2] - k[i]);
#pragma unroll
  for (int i = 0; i < 9; ++i) i3[i] = 1.0f / (k[i + 3] - k[i]);

  const int lane = threadIdx.x & 63;
  const int w = threadIdx.x >> 6;
  float* __restrict__ buf = lds[w];
  vf2* __restrict__ b2 = reinterpret_cast<vf2*>(buf);

  const vf2* __restrict__ x2 = reinterpret_cast<const vf2*>(x);
  const int gstr = gridDim.x * 4;
  int g = blockIdx.x * 4 + w;
  if (g >= nseg) return;

  // Depth-2 prefetch: loads for segments g and g+gstr in flight.
  vf2 xa = x2[(size_t)g * 64 + lane];
  vf2 xb;
  if (g + gstr < nseg) xb = x2[(size_t)(g + gstr) * 64 + lane];

  for (; g < nseg; g += gstr) {
    // ---- compute 2 elements, write column-major into wave's LDS region ----
    float Ba[2][8];
    compute_pair(xa, k, i1, i2, i3, Ba);
#pragma unroll
    for (int j = 0; j < 8; ++j) {
      vf2 v;
      v[0] = Ba[0][j];
      v[1] = Ba[1][j];
      b2[j * (SEG / 2) + lane] = v;  // lane stride 8 B, conflict-free
    }

    // Issue the prefetch for g+2*gstr; latency hides under the store phase
    // and the next iteration's compute.
    vf2 xc;
    if (g + 2 * gstr < nseg) xc = x2[(size_t)(g + 2 * gstr) * 64 + lane];

    // ---- transpose-read + coalesced NT store: 4 KiB per wave, contiguous.
    // Same-wave LDS RAW: LDS pipe is in-order per wave; compiler inserts the
    // lgkmcnt wait before v's use. No barrier needed.
    vf4* o4 = reinterpret_cast<vf4*>(out) + (size_t)g * 256;
#pragma unroll
    for (int s = 0; s < 4; ++s) {
      const int fi = s * 64 + lane;   // float4 index within segment
      const int le = fi >> 1;         // element 0..127
      const int j0 = (fi & 1) * 4;    // basis 0..3 or 4..7
      vf4 v;
      v[0] = buf[(j0 + 0) * SEG + le];  // 2-way bank alias only (free)
      v[1] = buf[(j0 + 1) * SEG + le];
      v[2] = buf[(j0 + 2) * SEG + le];
      v[3] = buf[(j0 + 3) * SEG + le];
      __builtin_nontemporal_store(v, &o4[fi]);  // 64 lanes x 16 B = 1 KiB
    }

    xa = xb;
    xb = xc;
  }
}

extern "C" void kernel_launch(void* const* d_in, const int* in_sizes, int n_in,
                              void* d_out, int out_size, void* d_ws, size_t ws_size,
                              hipStream_t stream) {
  const float* x = (const float*)d_in[0];
  const float* knots = (const float*)d_in[1];
  float* out = (float*)d_out;
  const int n = in_sizes[0];     // 8388608, divisible by SEG
  const int nseg = n / SEG;      // 65536 wave-segments
  const int blocks = 2048;       // 16 KiB LDS -> 8 blocks/CU, 32 waves/CU;
                                 // each wave handles exactly 8 segments
  bspline_kernel<<<blocks, 256, 0, stream>>>(x, knots, out, nseg);
}